// Round 8
// baseline (3697.543 us; speedup 1.0000x reference)
//
#include <hip/hip_runtime.h>
#include <hip/hip_bf16.h>
#include <math.h>

#define N_NODES 30000
#define N_EDGES 480000
#define N_GRAPH 64
#define DIN 24
#define HD 512
#define NL 6

typedef __hip_bfloat16 bf16;
using short8 = __attribute__((ext_vector_type(8))) short;
using f32x4 = __attribute__((ext_vector_type(4))) float;

// async 16B/lane global->LDS: lds dest = lp + lane*16 (wave-uniform lp!)
#define ASYNC16(gp, lp)                                              \
    __builtin_amdgcn_global_load_lds(                                \
        (const __attribute__((address_space(1))) void*)(gp),         \
        (__attribute__((address_space(3))) void*)(lp), 16, 0, 0)

__device__ __forceinline__ float sigmoidf_(float x) { return 1.0f / (1.0f + expf(-x)); }
__device__ __forceinline__ float b2f(unsigned short u) {
    return __uint_as_float(((unsigned int)u) << 16);
}
__device__ __forceinline__ unsigned short f2b(float f) {
    bf16 b = __float2bfloat16(f);
    return *(unsigned short*)&b;
}

// ---------------- encoder ---------------------------------------------------------
__global__ __launch_bounds__(256) void enc_kernel(const float* __restrict__ x,
                                                  const float* __restrict__ w,
                                                  const float* __restrict__ b,
                                                  bf16* __restrict__ h) {
    __shared__ float xs[DIN];
    int row = blockIdx.x;
    int tid = threadIdx.x;
    if (tid < DIN) xs[tid] = x[row * DIN + tid];
    __syncthreads();
    for (int c = tid; c < HD; c += 256) {
        float acc = b[c];
#pragma unroll
        for (int k = 0; k < DIN; k++) acc = fmaf(xs[k], w[k * HD + c], acc);
        h[(size_t)row * HD + c] = __float2bfloat16(acc);
    }
}

// ---------------- weight transpose + hi/lo split ----------------------------------
__global__ __launch_bounds__(256) void twcvt_kernel(const float* __restrict__ W,
                                                    bf16* __restrict__ WtH,
                                                    bf16* __restrict__ WtL, int Nc) {
    __shared__ float s[32][33];
    int l = blockIdx.z;
    const float* Wp = W + (size_t)l * HD * Nc;
    size_t ob = (size_t)l * HD * Nc;
    int k0 = blockIdx.y * 32, c0 = blockIdx.x * 32;
    int tx = threadIdx.x & 31, ty = threadIdx.x >> 5;
    for (int r = ty; r < 32; r += 8) s[r][tx] = Wp[(size_t)(k0 + r) * Nc + c0 + tx];
    __syncthreads();
    for (int r = ty; r < 32; r += 8) {
        float v = s[tx][r];
        unsigned short hu = f2b(v);
        float hf = b2f(hu);
        size_t o = ob + (size_t)(c0 + r) * HD + k0 + tx;
        *(unsigned short*)&WtH[o] = hu;
        WtL[o] = __float2bfloat16(v - hf);
    }
}

// ---------------- bf16 MFMA GEMM (hi/lo weights): tile 128x128 --------------------
// 4 waves x 32 rows x 128 cols; LDS = weight planes only (16 KB); A-fragments
// loaded directly from global (k-contiguous 16B). 4 blocks/CU.
// Staging: 128 cols = 8 chunks of 16 per buffer; wv0 BH ch0-3, wv1 BH ch4-7,
// wv2 BL ch0-3, wv3 BL ch4-7.  (R7 bug: 16 chunks -> OOB LDS write.)
template <bool RELU>
__global__ __launch_bounds__(256, 4) void gemm_mfma(const bf16* __restrict__ A,
                                                    const bf16* __restrict__ WtH,
                                                    const bf16* __restrict__ WtL,
                                                    const float* __restrict__ bias,
                                                    bf16* __restrict__ C, int n) {
    __shared__ bf16 BH[128 * 32];
    __shared__ bf16 BL[128 * 32];
    int tid = threadIdx.x;
    int wv = tid >> 6, lane = tid & 63;
    int quad = lane >> 4, l16 = lane & 15;
    int crow = lane >> 2, cseg = lane & 3;
    int gseg = cseg ^ ((crow >> 1) & 3);          // 2-way-free swizzle
    int fsw = (quad ^ ((l16 >> 1) & 3)) * 8;
    int row0 = blockIdx.y * 128, col0 = blockIdx.x * 128;
    f32x4 acc[2][8] = {};

    // A-fragment rows (clamped; dead rows guarded at write)
    int arow[2];
#pragma unroll
    for (int i = 0; i < 2; i++) {
        int r = row0 + wv * 32 + i * 16 + l16;
        arow[i] = (r < n) ? r : (n - 1);
    }
    const bf16* wb = (wv >= 2) ? WtL : WtH;
    bf16* bdst = (wv >= 2) ? BL : BH;
    int ch0 = (wv & 1) * 4;                       // 4 chunks per wave
    int boff[4];
#pragma unroll
    for (int s = 0; s < 4; s++) boff[s] = (col0 + (ch0 + s) * 16 + crow) * HD + gseg * 8;

    for (int kt = 0; kt < 512; kt += 32) {
#pragma unroll
        for (int s = 0; s < 4; s++) ASYNC16(&wb[boff[s] + kt], &bdst[(ch0 + s) * 512]);
        short8 af[2];
#pragma unroll
        for (int i = 0; i < 2; i++)
            af[i] = *(const short8*)&A[(size_t)arow[i] * HD + kt + quad * 8];
        __syncthreads();
#pragma unroll
        for (int t = 0; t < 8; t++) {
            int fo = (t * 16 + l16) * 32 + fsw;
            short8 bh = *(const short8*)&BH[fo];
            short8 bl = *(const short8*)&BL[fo];
#pragma unroll
            for (int i = 0; i < 2; i++) {
                acc[i][t] = __builtin_amdgcn_mfma_f32_16x16x32_bf16(af[i], bh, acc[i][t], 0, 0, 0);
                acc[i][t] = __builtin_amdgcn_mfma_f32_16x16x32_bf16(af[i], bl, acc[i][t], 0, 0, 0);
            }
        }
        __syncthreads();
    }
#pragma unroll
    for (int t = 0; t < 8; t++) {
        int col = col0 + t * 16 + l16;
        float bb = bias[col];
#pragma unroll
        for (int i = 0; i < 2; i++) {
#pragma unroll
            for (int r = 0; r < 4; r++) {
                int row = row0 + wv * 32 + i * 16 + quad * 4 + r;
                if (row < n) {
                    float v = acc[i][t][r] + bb;
                    if (RELU) v = fmaxf(v, 0.0f);
                    C[(size_t)row * HD + col] = __float2bfloat16(v);
                }
            }
        }
    }
}

// ---------------- fused GRU (MFMA, hi/lo, rz-concat accumulators) -----------------
// tile 128 rows x 64 cols, 4 waves x 32 rows; LDS = 12 weight planes (48 KB);
// M/H fragments loaded directly from global. 3 blocks/CU.
__global__ __launch_bounds__(256, 3) void gru_mfma(const bf16* __restrict__ M,
                                                   const bf16* __restrict__ Hc,
                                                   const bf16* __restrict__ WiH,
                                                   const bf16* __restrict__ WiL,
                                                   const bf16* __restrict__ WhH,
                                                   const bf16* __restrict__ WhL,
                                                   const float* __restrict__ bih,
                                                   const float* __restrict__ bhh,
                                                   bf16* __restrict__ Hn, int n) {
    __shared__ bf16 Ws[12 * 64 * 32];
    int tid = threadIdx.x;
    int wv = tid >> 6, lane = tid & 63;
    int quad = lane >> 4, l16 = lane & 15;
    int crow = lane >> 2, cseg = lane & 3;
    int gseg = cseg ^ ((crow >> 1) & 3);
    int fsw = (quad ^ ((l16 >> 1) & 3)) * 8;
    int row0 = blockIdx.y * 128, col0 = blockIdx.x * 64;
    f32x4 aR[2][4] = {}, aZ[2][4] = {}, aI[2][4] = {}, aHn[2][4] = {};

    int arow[2];
#pragma unroll
    for (int i = 0; i < 2; i++) {
        int r = row0 + wv * 32 + i * 16 + l16;
        arow[i] = (r < n) ? r : (n - 1);
    }
    // each wave stages 3 of 12 planes (plane = 64 rows = 4 chunks of 16)
    const bf16* wbase[4] = {WiH, WiL, WhH, WhL};
    const bf16* wgp[3];
    int wlds[3];
#pragma unroll
    for (int pp = 0; pp < 3; pp++) {
        int p = wv * 3 + pp;                  // 0..11
        int mat = (p >= 6);
        int q = p - mat * 6;
        int g = q >> 1, pl = q & 1;
        const bf16* base = wbase[mat * 2 + pl] + (size_t)(g * HD + col0) * HD;
        wgp[pp] = base + crow * HD + gseg * 8;
        wlds[pp] = p * 2048;
    }

    for (int kt = 0; kt < 512; kt += 32) {
#pragma unroll
        for (int pp = 0; pp < 3; pp++)
#pragma unroll
            for (int s = 0; s < 4; s++)
                ASYNC16(wgp[pp] + (size_t)s * 16 * HD + kt, &Ws[wlds[pp] + s * 512]);
        short8 am[2], ah[2];
#pragma unroll
        for (int i = 0; i < 2; i++) {
            am[i] = *(const short8*)&M[(size_t)arow[i] * HD + kt + quad * 8];
            ah[i] = *(const short8*)&Hc[(size_t)arow[i] * HD + kt + quad * 8];
        }
        __syncthreads();
#pragma unroll
        for (int t = 0; t < 4; t++) {
            int fo = (t * 16 + l16) * 32 + fsw;
            short8 wrh = *(const short8*)&Ws[0 * 2048 + fo];
            short8 wrl = *(const short8*)&Ws[1 * 2048 + fo];
            short8 wzh = *(const short8*)&Ws[2 * 2048 + fo];
            short8 wzl = *(const short8*)&Ws[3 * 2048 + fo];
            short8 wnh = *(const short8*)&Ws[4 * 2048 + fo];
            short8 wnl = *(const short8*)&Ws[5 * 2048 + fo];
            short8 vrh = *(const short8*)&Ws[6 * 2048 + fo];
            short8 vrl = *(const short8*)&Ws[7 * 2048 + fo];
            short8 vzh = *(const short8*)&Ws[8 * 2048 + fo];
            short8 vzl = *(const short8*)&Ws[9 * 2048 + fo];
            short8 vnh = *(const short8*)&Ws[10 * 2048 + fo];
            short8 vnl = *(const short8*)&Ws[11 * 2048 + fo];
#pragma unroll
            for (int i = 0; i < 2; i++) {
                aR[i][t] = __builtin_amdgcn_mfma_f32_16x16x32_bf16(am[i], wrh, aR[i][t], 0, 0, 0);
                aR[i][t] = __builtin_amdgcn_mfma_f32_16x16x32_bf16(am[i], wrl, aR[i][t], 0, 0, 0);
                aR[i][t] = __builtin_amdgcn_mfma_f32_16x16x32_bf16(ah[i], vrh, aR[i][t], 0, 0, 0);
                aR[i][t] = __builtin_amdgcn_mfma_f32_16x16x32_bf16(ah[i], vrl, aR[i][t], 0, 0, 0);
                aZ[i][t] = __builtin_amdgcn_mfma_f32_16x16x32_bf16(am[i], wzh, aZ[i][t], 0, 0, 0);
                aZ[i][t] = __builtin_amdgcn_mfma_f32_16x16x32_bf16(am[i], wzl, aZ[i][t], 0, 0, 0);
                aZ[i][t] = __builtin_amdgcn_mfma_f32_16x16x32_bf16(ah[i], vzh, aZ[i][t], 0, 0, 0);
                aZ[i][t] = __builtin_amdgcn_mfma_f32_16x16x32_bf16(ah[i], vzl, aZ[i][t], 0, 0, 0);
                aI[i][t] = __builtin_amdgcn_mfma_f32_16x16x32_bf16(am[i], wnh, aI[i][t], 0, 0, 0);
                aI[i][t] = __builtin_amdgcn_mfma_f32_16x16x32_bf16(am[i], wnl, aI[i][t], 0, 0, 0);
                aHn[i][t] = __builtin_amdgcn_mfma_f32_16x16x32_bf16(ah[i], vnh, aHn[i][t], 0, 0, 0);
                aHn[i][t] = __builtin_amdgcn_mfma_f32_16x16x32_bf16(ah[i], vnl, aHn[i][t], 0, 0, 0);
            }
        }
        __syncthreads();
    }
    const unsigned short* hp = (const unsigned short*)Hc;
#pragma unroll
    for (int t = 0; t < 4; t++) {
        int col = col0 + t * 16 + l16;
        float brz = bih[col] + bhh[col];
        float bzz = bih[HD + col] + bhh[HD + col];
        float bin_ = bih[2 * HD + col];
        float bhn_ = bhh[2 * HD + col];
#pragma unroll
        for (int i = 0; i < 2; i++) {
#pragma unroll
            for (int r = 0; r < 4; r++) {
                int row = row0 + wv * 32 + i * 16 + quad * 4 + r;
                if (row < n) {
                    float rg = sigmoidf_(aR[i][t][r] + brz);
                    float zg = sigmoidf_(aZ[i][t][r] + bzz);
                    float ng = tanhf(aI[i][t][r] + bin_ + rg * (aHn[i][t][r] + bhn_));
                    float hold = b2f(hp[(size_t)row * HD + col]);
                    Hn[(size_t)row * HD + col] = __float2bfloat16((1.0f - zg) * ng + zg * hold);
                }
            }
        }
    }
}

// ---------------- CSR build -------------------------------------------------------
__global__ __launch_bounds__(256) void deg_kernel(const int* __restrict__ dst,
                                                  int* __restrict__ deg) {
    int e = blockIdx.x * 256 + threadIdx.x;
    if (e < N_EDGES) atomicAdd(&deg[dst[e]], 1);
}

__global__ __launch_bounds__(1024) void scan_kernel(const int* __restrict__ deg,
                                                    int* __restrict__ offs) {
    __shared__ int buf[1024];
    __shared__ int carry_s;
    int tid = threadIdx.x;
    if (tid == 0) carry_s = 0;
    __syncthreads();
    for (int base = 0; base < N_NODES; base += 1024) {
        int v = (base + tid < N_NODES) ? deg[base + tid] : 0;
        buf[tid] = v;
        __syncthreads();
        for (int s = 1; s < 1024; s <<= 1) {
            int t = (tid >= s) ? buf[tid - s] : 0;
            __syncthreads();
            buf[tid] += t;
            __syncthreads();
        }
        int incl = buf[tid];
        if (base + tid < N_NODES) offs[base + tid] = carry_s + incl - v;
        __syncthreads();
        if (tid == 0) carry_s += buf[1023];
        __syncthreads();
    }
    if (tid == 0) offs[N_NODES] = carry_s;
}

__global__ __launch_bounds__(256) void bucket_kernel(const int* __restrict__ src,
                                                     const int* __restrict__ dst,
                                                     const int* __restrict__ offs,
                                                     int* __restrict__ cursor,
                                                     unsigned short* __restrict__ elist) {
    int e = blockIdx.x * 256 + threadIdx.x;
    if (e >= N_EDGES) return;
    int d = dst[e];
    int pos = atomicAdd(&cursor[d], 1);
    elist[offs[d] + pos] = (unsigned short)src[e];
}

// ---------------- gather-sum ------------------------------------------------------
__global__ __launch_bounds__(256) void gather_kernel(const bf16* __restrict__ msg,
                                                     bf16* __restrict__ m,
                                                     const unsigned short* __restrict__ elist,
                                                     const int* __restrict__ offs) {
    int nid = blockIdx.x, tid = threadIdx.x;
    int beg = offs[nid], end = offs[nid + 1];
    const unsigned int* mp = (const unsigned int*)msg;
    unsigned int u = mp[(size_t)nid * 256 + tid];
    float ax = b2f((unsigned short)(u & 0xffffu));
    float ay = b2f((unsigned short)(u >> 16));
    int e = beg;
    for (; e + 3 < end; e += 4) {
        unsigned int v0 = mp[(size_t)elist[e] * 256 + tid];
        unsigned int v1 = mp[(size_t)elist[e + 1] * 256 + tid];
        unsigned int v2 = mp[(size_t)elist[e + 2] * 256 + tid];
        unsigned int v3 = mp[(size_t)elist[e + 3] * 256 + tid];
        ax += b2f((unsigned short)(v0 & 0xffffu)) + b2f((unsigned short)(v1 & 0xffffu)) +
              b2f((unsigned short)(v2 & 0xffffu)) + b2f((unsigned short)(v3 & 0xffffu));
        ay += b2f((unsigned short)(v0 >> 16)) + b2f((unsigned short)(v1 >> 16)) +
              b2f((unsigned short)(v2 >> 16)) + b2f((unsigned short)(v3 >> 16));
    }
    for (; e < end; e++) {
        unsigned int v0 = mp[(size_t)elist[e] * 256 + tid];
        ax += b2f((unsigned short)(v0 & 0xffffu));
        ay += b2f((unsigned short)(v0 >> 16));
    }
    unsigned int out = ((unsigned int)f2b(ay) << 16) | (unsigned int)f2b(ax);
    ((unsigned int*)m)[(size_t)nid * 256 + tid] = out;
}

// ---------------- pooling (segmented, batch sorted -> no atomics) -----------------
__global__ __launch_bounds__(256) void pool_kernel(const bf16* __restrict__ h,
                                                   const int* __restrict__ batch,
                                                   float* __restrict__ pooled,
                                                   float* __restrict__ cnt) {
    int g = blockIdx.x;
    int col = blockIdx.y * 256 + threadIdx.x;
    int lo = 0, hi = N_NODES;
    while (lo < hi) { int mid = (lo + hi) >> 1; if (batch[mid] < g) lo = mid + 1; else hi = mid; }
    int gs = lo;
    hi = N_NODES;
    while (lo < hi) { int mid = (lo + hi) >> 1; if (batch[mid] < g + 1) lo = mid + 1; else hi = mid; }
    int ge = lo;
    const unsigned short* hp = (const unsigned short*)h;
    float acc = 0.0f;
    int r = gs;
    for (; r + 3 < ge; r += 4) {
        acc += b2f(hp[(size_t)r * HD + col]) + b2f(hp[(size_t)(r + 1) * HD + col]) +
               b2f(hp[(size_t)(r + 2) * HD + col]) + b2f(hp[(size_t)(r + 3) * HD + col]);
    }
    for (; r < ge; r++) acc += b2f(hp[(size_t)r * HD + col]);
    pooled[g * HD + col] = acc;
    if (blockIdx.y == 0 && threadIdx.x == 0) cnt[g] = (float)(ge - gs);
}

__global__ __launch_bounds__(256) void head_kernel(const float* __restrict__ pooled,
                                                   const float* __restrict__ cnt,
                                                   const float* __restrict__ w1,
                                                   const float* __restrict__ b1,
                                                   const float* __restrict__ w2,
                                                   const float* __restrict__ b2,
                                                   float* __restrict__ out) {
    __shared__ float prow[HD];
    __shared__ float red[256];
    int g = blockIdx.x, tid = threadIdx.x;
    float c = fmaxf(cnt[g], 1.0f);
    for (int j = tid; j < HD; j += 256) prow[j] = pooled[g * HD + j] / c;
    __syncthreads();
    float acc = b1[tid];
    for (int k = 0; k < HD; k++) acc = fmaf(prow[k], w1[k * 256 + tid], acc);
    red[tid] = fmaxf(acc, 0.0f) * w2[tid];
    __syncthreads();
    for (int s = 128; s > 0; s >>= 1) {
        if (tid < s) red[tid] += red[tid + s];
        __syncthreads();
    }
    if (tid == 0) out[g] = red[0] + b2[0];
}

// ---------------- launch ----------------------------------------------------------
extern "C" void kernel_launch(void* const* d_in, const int* in_sizes, int n_in,
                              void* d_out, int out_size, void* d_ws, size_t ws_size,
                              hipStream_t stream) {
    const float* x = (const float*)d_in[0];
    const int* eidx = (const int*)d_in[1];
    const int* batch = (const int*)d_in[2];
    const float* enc_w = (const float*)d_in[3];
    const float* enc_b = (const float*)d_in[4];
    const float* mlp_w1 = (const float*)d_in[5];
    const float* mlp_b1 = (const float*)d_in[6];
    const float* mlp_w2 = (const float*)d_in[7];
    const float* mlp_b2 = (const float*)d_in[8];
    const float* gru_wih = (const float*)d_in[9];
    const float* gru_whh = (const float*)d_in[10];
    const float* gru_bih = (const float*)d_in[11];
    const float* gru_bhh = (const float*)d_in[12];
    const float* head_w1 = (const float*)d_in[13];
    const float* head_b1 = (const float*)d_in[14];
    const float* head_w2 = (const float*)d_in[15];
    const float* head_b2 = (const float*)d_in[16];
    const int* src = eidx;
    const int* dst = eidx + N_EDGES;

    const size_t NH = (size_t)N_NODES * HD;
    char* p = (char*)d_ws;
    auto alloc = [&](size_t bytes) { char* q = p; p += (bytes + 255) & ~(size_t)255; return q; };
    bf16* S0 = (bf16*)alloc(NH * 2);
    bf16* S1 = (bf16*)alloc(NH * 2);
    bf16* S2 = (bf16*)alloc(NH * 2);
    bf16* w1tH = (bf16*)alloc((size_t)NL * HD * HD * 2);
    bf16* w1tL = (bf16*)alloc((size_t)NL * HD * HD * 2);
    bf16* w2tH = (bf16*)alloc((size_t)NL * HD * HD * 2);
    bf16* w2tL = (bf16*)alloc((size_t)NL * HD * HD * 2);
    bf16* wihtH = (bf16*)alloc((size_t)NL * 3 * HD * HD * 2);
    bf16* wihtL = (bf16*)alloc((size_t)NL * 3 * HD * HD * 2);
    bf16* whhtH = (bf16*)alloc((size_t)NL * 3 * HD * HD * 2);
    bf16* whhtL = (bf16*)alloc((size_t)NL * 3 * HD * HD * 2);
    float* pooled = (float*)alloc((size_t)N_GRAPH * HD * 4);
    float* cnt = (float*)alloc(N_GRAPH * 4);
    int* deg = (int*)alloc((N_NODES + 1) * 4);  // also cursor
    int* offs = (int*)alloc((N_NODES + 1) * 4);
    unsigned short* elist = (unsigned short*)alloc((size_t)N_EDGES * 2);
    // total ~144 MB (proven-safe envelope)

    twcvt_kernel<<<dim3(16, 16, NL), 256, 0, stream>>>(mlp_w1, w1tH, w1tL, HD);
    twcvt_kernel<<<dim3(16, 16, NL), 256, 0, stream>>>(mlp_w2, w2tH, w2tL, HD);
    twcvt_kernel<<<dim3(48, 16, NL), 256, 0, stream>>>(gru_wih, wihtH, wihtL, 3 * HD);
    twcvt_kernel<<<dim3(48, 16, NL), 256, 0, stream>>>(gru_whh, whhtH, whhtL, 3 * HD);

    hipMemsetAsync(deg, 0, (N_NODES + 1) * sizeof(int), stream);
    deg_kernel<<<(N_EDGES + 255) / 256, 256, 0, stream>>>(dst, deg);
    scan_kernel<<<1, 1024, 0, stream>>>(deg, offs);
    hipMemsetAsync(deg, 0, (N_NODES + 1) * sizeof(int), stream);
    bucket_kernel<<<(N_EDGES + 255) / 256, 256, 0, stream>>>(src, dst, offs, deg, elist);

    enc_kernel<<<N_NODES, 256, 0, stream>>>(x, enc_w, enc_b, S0);

    bf16* hcur = S0;
    bf16* hoth = S1;
    dim3 ggrid(4, (N_NODES + 127) / 128);   // 128-col tiles
    dim3 ugrid(8, (N_NODES + 127) / 128);

    for (int l = 0; l < NL; l++) {
        size_t wsq = (size_t)l * HD * HD;
        size_t wgq = (size_t)l * 3 * HD * HD;
        const float* b1 = mlp_b1 + (size_t)l * HD;
        const float* b2 = mlp_b2 + (size_t)l * HD;
        const float* bih = gru_bih + (size_t)l * 3 * HD;
        const float* bhh = gru_bhh + (size_t)l * 3 * HD;

        gemm_mfma<true><<<ggrid, 256, 0, stream>>>(hcur, w1tH + wsq, w1tL + wsq, b1, hoth, N_NODES);
        gemm_mfma<false><<<ggrid, 256, 0, stream>>>(hoth, w2tH + wsq, w2tL + wsq, b2, S2, N_NODES);
        gather_kernel<<<N_NODES, 256, 0, stream>>>(S2, hoth, elist, offs);
        gru_mfma<<<ugrid, 256, 0, stream>>>(hoth, hcur, wihtH + wgq, wihtL + wgq,
                                            whhtH + wgq, whhtL + wgq, bih, bhh, S2, N_NODES);
        bf16* newh = S2;
        S2 = hcur;
        hcur = newh;
    }

    pool_kernel<<<dim3(N_GRAPH, 2), 256, 0, stream>>>(hcur, batch, pooled, cnt);
    head_kernel<<<N_GRAPH, 256, 0, stream>>>(pooled, cnt, head_w1, head_b1, head_w2, head_b2,
                                             (float*)d_out);
}

// Round 9
// 2914.529 us; speedup vs baseline: 1.2687x; 1.2687x over previous
//
#include <hip/hip_runtime.h>
#include <hip/hip_bf16.h>
#include <math.h>

#define N_NODES 30000
#define N_EDGES 480000
#define N_GRAPH 64
#define DIN 24
#define HD 512
#define NL 6
#define NRB 235   // ceil(30000/128) row blocks

typedef __hip_bfloat16 bf16;
using short8 = __attribute__((ext_vector_type(8))) short;
using f32x4 = __attribute__((ext_vector_type(4))) float;

// async 16B/lane global->LDS: lds dest = lp + lane*16 (wave-uniform lp!)
#define ASYNC16(gp, lp)                                              \
    __builtin_amdgcn_global_load_lds(                                \
        (const __attribute__((address_space(1))) void*)(gp),         \
        (__attribute__((address_space(3))) void*)(lp), 16, 0, 0)

__device__ __forceinline__ float sigmoidf_(float x) { return 1.0f / (1.0f + expf(-x)); }
__device__ __forceinline__ float b2f(unsigned short u) {
    return __uint_as_float(((unsigned int)u) << 16);
}
__device__ __forceinline__ unsigned short f2b(float f) {
    bf16 b = __float2bfloat16(f);
    return *(unsigned short*)&b;
}

// ---------------- encoder ---------------------------------------------------------
__global__ __launch_bounds__(256) void enc_kernel(const float* __restrict__ x,
                                                  const float* __restrict__ w,
                                                  const float* __restrict__ b,
                                                  bf16* __restrict__ h) {
    __shared__ float xs[DIN];
    int row = blockIdx.x;
    int tid = threadIdx.x;
    if (tid < DIN) xs[tid] = x[row * DIN + tid];
    __syncthreads();
    for (int c = tid; c < HD; c += 256) {
        float acc = b[c];
#pragma unroll
        for (int k = 0; k < DIN; k++) acc = fmaf(xs[k], w[k * HD + c], acc);
        h[(size_t)row * HD + c] = __float2bfloat16(acc);
    }
}

// ---------------- weight transpose + hi/lo split ----------------------------------
__global__ __launch_bounds__(256) void twcvt_kernel(const float* __restrict__ W,
                                                    bf16* __restrict__ WtH,
                                                    bf16* __restrict__ WtL, int Nc) {
    __shared__ float s[32][33];
    int l = blockIdx.z;
    const float* Wp = W + (size_t)l * HD * Nc;
    size_t ob = (size_t)l * HD * Nc;
    int k0 = blockIdx.y * 32, c0 = blockIdx.x * 32;
    int tx = threadIdx.x & 31, ty = threadIdx.x >> 5;
    for (int r = ty; r < 32; r += 8) s[r][tx] = Wp[(size_t)(k0 + r) * Nc + c0 + tx];
    __syncthreads();
    for (int r = ty; r < 32; r += 8) {
        float v = s[tx][r];
        unsigned short hu = f2b(v);
        float hf = b2f(hu);
        size_t o = ob + (size_t)(c0 + r) * HD + k0 + tx;
        *(unsigned short*)&WtH[o] = hu;
        WtL[o] = __float2bfloat16(v - hf);
    }
}

// ---------------- bf16 MFMA GEMM (hi/lo weights): tile 128x128 --------------------
// R6 structure (all-LDS staging); 1-D col-major-swizzled grid for weight L2 locality.
template <bool RELU>
__global__ __launch_bounds__(256) void gemm_mfma(const bf16* __restrict__ A,
                                                 const bf16* __restrict__ WtH,
                                                 const bf16* __restrict__ WtL,
                                                 const float* __restrict__ bias,
                                                 bf16* __restrict__ C, int n) {
    __shared__ bf16 As[128 * 32];
    __shared__ bf16 BH[128 * 32];
    __shared__ bf16 BL[128 * 32];
    int tid = threadIdx.x;
    int wv = tid >> 6, lane = tid & 63;
    int quad = lane >> 4, l16 = lane & 15;
    int crow = lane >> 2, cseg = lane & 3;
    int gseg = cseg ^ ((crow >> 1) & 3);          // 2-way-free swizzle
    int fsw = (quad ^ ((l16 >> 1) & 3)) * 8;
    int bid = blockIdx.x;
    int row0 = (bid % NRB) * 128, col0 = (bid / NRB) * 128;   // col-major order
    f32x4 acc[2][8] = {};

    int aoff[4], alds[4];
    int boff[8];
    const bf16* wb = (wv == 2) ? WtH : WtL;
    bf16* bdst = (wv == 2) ? BH : BL;
    if (wv < 2) {
#pragma unroll
        for (int j = 0; j < 4; j++) {
            int ch = wv * 4 + j;                  // 0..7 row chunk
            int gr = row0 + ch * 16 + crow;
            if (gr > n - 1) gr = n - 1;           // clamp; dead rows guarded at write
            aoff[j] = gr * HD + gseg * 8;
            alds[j] = ch * 512;
        }
    } else {
#pragma unroll
        for (int s = 0; s < 8; s++) boff[s] = (col0 + s * 16 + crow) * HD + gseg * 8;
    }

    for (int kt = 0; kt < 512; kt += 32) {
        if (wv < 2) {
#pragma unroll
            for (int j = 0; j < 4; j++) ASYNC16(&A[aoff[j] + kt], &As[alds[j]]);
        } else {
#pragma unroll
            for (int s = 0; s < 8; s++) ASYNC16(&wb[boff[s] + kt], &bdst[s * 512]);
        }
        __syncthreads();
        short8 af[2];
#pragma unroll
        for (int i = 0; i < 2; i++)
            af[i] = *(const short8*)&As[(wv * 32 + i * 16 + l16) * 32 + fsw];
#pragma unroll
        for (int t = 0; t < 8; t++) {
            int fo = (t * 16 + l16) * 32 + fsw;
            short8 bh = *(const short8*)&BH[fo];
            short8 bl = *(const short8*)&BL[fo];
#pragma unroll
            for (int i = 0; i < 2; i++) {
                acc[i][t] = __builtin_amdgcn_mfma_f32_16x16x32_bf16(af[i], bh, acc[i][t], 0, 0, 0);
                acc[i][t] = __builtin_amdgcn_mfma_f32_16x16x32_bf16(af[i], bl, acc[i][t], 0, 0, 0);
            }
        }
        __syncthreads();
    }
#pragma unroll
    for (int t = 0; t < 8; t++) {
        int col = col0 + t * 16 + l16;
        float bb = bias[col];
#pragma unroll
        for (int i = 0; i < 2; i++) {
#pragma unroll
            for (int r = 0; r < 4; r++) {
                int row = row0 + wv * 32 + i * 16 + quad * 4 + r;
                if (row < n) {
                    float v = acc[i][t][r] + bb;
                    if (RELU) v = fmaxf(v, 0.0f);
                    C[(size_t)row * HD + col] = __float2bfloat16(v);
                }
            }
        }
    }
}

// ---------------- fused GRU (MFMA, hi/lo, rz-concat accumulators) -----------------
// R6 structure: tile 128x64, LDS 64 KB (Ms+Hs+12 planes), 2 blocks/CU;
// 1-D col-major-swizzled grid for weight L2 locality.
__global__ __launch_bounds__(256, 2) void gru_mfma(const bf16* __restrict__ M,
                                                   const bf16* __restrict__ Hc,
                                                   const bf16* __restrict__ WiH,
                                                   const bf16* __restrict__ WiL,
                                                   const bf16* __restrict__ WhH,
                                                   const bf16* __restrict__ WhL,
                                                   const float* __restrict__ bih,
                                                   const float* __restrict__ bhh,
                                                   bf16* __restrict__ Hn, int n) {
    __shared__ bf16 Ms[128 * 32];
    __shared__ bf16 Hs[128 * 32];
    __shared__ bf16 Ws[12 * 64 * 32];
    int tid = threadIdx.x;
    int wv = tid >> 6, lane = tid & 63;
    int quad = lane >> 4, l16 = lane & 15;
    int crow = lane >> 2, cseg = lane & 3;
    int gseg = cseg ^ ((crow >> 1) & 3);
    int fsw = (quad ^ ((l16 >> 1) & 3)) * 8;
    int bid = blockIdx.x;
    int row0 = (bid % NRB) * 128, col0 = (bid / NRB) * 64;    // col-major order
    f32x4 aR[2][4] = {}, aZ[2][4] = {}, aI[2][4] = {}, aHn[2][4] = {};

    int moff[8];
    const bf16* wgp[4];
    int wlds[4];
    if (wv == 0) {
#pragma unroll
        for (int j = 0; j < 8; j++) {
            int gr = row0 + j * 16 + crow;
            if (gr > n - 1) gr = n - 1;
            moff[j] = gr * HD + gseg * 8;
        }
    } else {
        const bf16* wbase[4] = {WiH, WiL, WhH, WhL};
#pragma unroll
        for (int pp = 0; pp < 4; pp++) {
            int p = (wv - 1) * 4 + pp;            // 0..11
            int mat = (p >= 6);
            int q = p - mat * 6;
            int g = q >> 1, pl = q & 1;
            const bf16* base = wbase[mat * 2 + pl] + (size_t)(g * HD + col0) * HD;
            wgp[pp] = base + crow * HD + gseg * 8;
            wlds[pp] = p * 2048;
        }
    }

    for (int kt = 0; kt < 512; kt += 32) {
        if (wv == 0) {
#pragma unroll
            for (int j = 0; j < 8; j++) {
                ASYNC16(&M[moff[j] + kt], &Ms[j * 512]);
                ASYNC16(&Hc[moff[j] + kt], &Hs[j * 512]);
            }
        } else {
#pragma unroll
            for (int pp = 0; pp < 4; pp++)
#pragma unroll
                for (int s = 0; s < 4; s++)
                    ASYNC16(wgp[pp] + (size_t)s * 16 * HD + kt, &Ws[wlds[pp] + s * 512]);
        }
        __syncthreads();
        short8 am[2], ah[2];
#pragma unroll
        for (int i = 0; i < 2; i++) {
            am[i] = *(const short8*)&Ms[(wv * 32 + i * 16 + l16) * 32 + fsw];
            ah[i] = *(const short8*)&Hs[(wv * 32 + i * 16 + l16) * 32 + fsw];
        }
#pragma unroll
        for (int t = 0; t < 4; t++) {
            int fo = (t * 16 + l16) * 32 + fsw;
            short8 wrh = *(const short8*)&Ws[0 * 2048 + fo];
            short8 wrl = *(const short8*)&Ws[1 * 2048 + fo];
            short8 wzh = *(const short8*)&Ws[2 * 2048 + fo];
            short8 wzl = *(const short8*)&Ws[3 * 2048 + fo];
            short8 wnh = *(const short8*)&Ws[4 * 2048 + fo];
            short8 wnl = *(const short8*)&Ws[5 * 2048 + fo];
            short8 vrh = *(const short8*)&Ws[6 * 2048 + fo];
            short8 vrl = *(const short8*)&Ws[7 * 2048 + fo];
            short8 vzh = *(const short8*)&Ws[8 * 2048 + fo];
            short8 vzl = *(const short8*)&Ws[9 * 2048 + fo];
            short8 vnh = *(const short8*)&Ws[10 * 2048 + fo];
            short8 vnl = *(const short8*)&Ws[11 * 2048 + fo];
#pragma unroll
            for (int i = 0; i < 2; i++) {
                aR[i][t] = __builtin_amdgcn_mfma_f32_16x16x32_bf16(am[i], wrh, aR[i][t], 0, 0, 0);
                aR[i][t] = __builtin_amdgcn_mfma_f32_16x16x32_bf16(am[i], wrl, aR[i][t], 0, 0, 0);
                aR[i][t] = __builtin_amdgcn_mfma_f32_16x16x32_bf16(ah[i], vrh, aR[i][t], 0, 0, 0);
                aR[i][t] = __builtin_amdgcn_mfma_f32_16x16x32_bf16(ah[i], vrl, aR[i][t], 0, 0, 0);
                aZ[i][t] = __builtin_amdgcn_mfma_f32_16x16x32_bf16(am[i], wzh, aZ[i][t], 0, 0, 0);
                aZ[i][t] = __builtin_amdgcn_mfma_f32_16x16x32_bf16(am[i], wzl, aZ[i][t], 0, 0, 0);
                aZ[i][t] = __builtin_amdgcn_mfma_f32_16x16x32_bf16(ah[i], vzh, aZ[i][t], 0, 0, 0);
                aZ[i][t] = __builtin_amdgcn_mfma_f32_16x16x32_bf16(ah[i], vzl, aZ[i][t], 0, 0, 0);
                aI[i][t] = __builtin_amdgcn_mfma_f32_16x16x32_bf16(am[i], wnh, aI[i][t], 0, 0, 0);
                aI[i][t] = __builtin_amdgcn_mfma_f32_16x16x32_bf16(am[i], wnl, aI[i][t], 0, 0, 0);
                aHn[i][t] = __builtin_amdgcn_mfma_f32_16x16x32_bf16(ah[i], vnh, aHn[i][t], 0, 0, 0);
                aHn[i][t] = __builtin_amdgcn_mfma_f32_16x16x32_bf16(ah[i], vnl, aHn[i][t], 0, 0, 0);
            }
        }
        __syncthreads();
    }
    const unsigned short* hp = (const unsigned short*)Hc;
#pragma unroll
    for (int t = 0; t < 4; t++) {
        int col = col0 + t * 16 + l16;
        float brz = bih[col] + bhh[col];
        float bzz = bih[HD + col] + bhh[HD + col];
        float bin_ = bih[2 * HD + col];
        float bhn_ = bhh[2 * HD + col];
#pragma unroll
        for (int i = 0; i < 2; i++) {
#pragma unroll
            for (int r = 0; r < 4; r++) {
                int row = row0 + wv * 32 + i * 16 + quad * 4 + r;
                if (row < n) {
                    float rg = sigmoidf_(aR[i][t][r] + brz);
                    float zg = sigmoidf_(aZ[i][t][r] + bzz);
                    float ng = tanhf(aI[i][t][r] + bin_ + rg * (aHn[i][t][r] + bhn_));
                    float hold = b2f(hp[(size_t)row * HD + col]);
                    Hn[(size_t)row * HD + col] = __float2bfloat16((1.0f - zg) * ng + zg * hold);
                }
            }
        }
    }
}

// ---------------- CSR build -------------------------------------------------------
__global__ __launch_bounds__(256) void deg_kernel(const int* __restrict__ dst,
                                                  int* __restrict__ deg) {
    int e = blockIdx.x * 256 + threadIdx.x;
    if (e < N_EDGES) atomicAdd(&deg[dst[e]], 1);
}

__global__ __launch_bounds__(1024) void scan_kernel(const int* __restrict__ deg,
                                                    int* __restrict__ offs) {
    __shared__ int buf[1024];
    __shared__ int carry_s;
    int tid = threadIdx.x;
    if (tid == 0) carry_s = 0;
    __syncthreads();
    for (int base = 0; base < N_NODES; base += 1024) {
        int v = (base + tid < N_NODES) ? deg[base + tid] : 0;
        buf[tid] = v;
        __syncthreads();
        for (int s = 1; s < 1024; s <<= 1) {
            int t = (tid >= s) ? buf[tid - s] : 0;
            __syncthreads();
            buf[tid] += t;
            __syncthreads();
        }
        int incl = buf[tid];
        if (base + tid < N_NODES) offs[base + tid] = carry_s + incl - v;
        __syncthreads();
        if (tid == 0) carry_s += buf[1023];
        __syncthreads();
    }
    if (tid == 0) offs[N_NODES] = carry_s;
}

__global__ __launch_bounds__(256) void bucket_kernel(const int* __restrict__ src,
                                                     const int* __restrict__ dst,
                                                     const int* __restrict__ offs,
                                                     int* __restrict__ cursor,
                                                     unsigned short* __restrict__ elist) {
    int e = blockIdx.x * 256 + threadIdx.x;
    if (e >= N_EDGES) return;
    int d = dst[e];
    int pos = atomicAdd(&cursor[d], 1);
    elist[offs[d] + pos] = (unsigned short)src[e];
}

// ---------------- gather-sum ------------------------------------------------------
__global__ __launch_bounds__(256) void gather_kernel(const bf16* __restrict__ msg,
                                                     bf16* __restrict__ m,
                                                     const unsigned short* __restrict__ elist,
                                                     const int* __restrict__ offs) {
    int nid = blockIdx.x, tid = threadIdx.x;
    int beg = offs[nid], end = offs[nid + 1];
    const unsigned int* mp = (const unsigned int*)msg;
    unsigned int u = mp[(size_t)nid * 256 + tid];
    float ax = b2f((unsigned short)(u & 0xffffu));
    float ay = b2f((unsigned short)(u >> 16));
    int e = beg;
    for (; e + 3 < end; e += 4) {
        unsigned int v0 = mp[(size_t)elist[e] * 256 + tid];
        unsigned int v1 = mp[(size_t)elist[e + 1] * 256 + tid];
        unsigned int v2 = mp[(size_t)elist[e + 2] * 256 + tid];
        unsigned int v3 = mp[(size_t)elist[e + 3] * 256 + tid];
        ax += b2f((unsigned short)(v0 & 0xffffu)) + b2f((unsigned short)(v1 & 0xffffu)) +
              b2f((unsigned short)(v2 & 0xffffu)) + b2f((unsigned short)(v3 & 0xffffu));
        ay += b2f((unsigned short)(v0 >> 16)) + b2f((unsigned short)(v1 >> 16)) +
              b2f((unsigned short)(v2 >> 16)) + b2f((unsigned short)(v3 >> 16));
    }
    for (; e < end; e++) {
        unsigned int v0 = mp[(size_t)elist[e] * 256 + tid];
        ax += b2f((unsigned short)(v0 & 0xffffu));
        ay += b2f((unsigned short)(v0 >> 16));
    }
    unsigned int out = ((unsigned int)f2b(ay) << 16) | (unsigned int)f2b(ax);
    ((unsigned int*)m)[(size_t)nid * 256 + tid] = out;
}

// ---------------- pooling (segmented, batch sorted -> no atomics) -----------------
__global__ __launch_bounds__(256) void pool_kernel(const bf16* __restrict__ h,
                                                   const int* __restrict__ batch,
                                                   float* __restrict__ pooled,
                                                   float* __restrict__ cnt) {
    int g = blockIdx.x;
    int col = blockIdx.y * 256 + threadIdx.x;
    int lo = 0, hi = N_NODES;
    while (lo < hi) { int mid = (lo + hi) >> 1; if (batch[mid] < g) lo = mid + 1; else hi = mid; }
    int gs = lo;
    hi = N_NODES;
    while (lo < hi) { int mid = (lo + hi) >> 1; if (batch[mid] < g + 1) lo = mid + 1; else hi = mid; }
    int ge = lo;
    const unsigned short* hp = (const unsigned short*)h;
    float acc = 0.0f;
    int r = gs;
    for (; r + 3 < ge; r += 4) {
        acc += b2f(hp[(size_t)r * HD + col]) + b2f(hp[(size_t)(r + 1) * HD + col]) +
               b2f(hp[(size_t)(r + 2) * HD + col]) + b2f(hp[(size_t)(r + 3) * HD + col]);
    }
    for (; r < ge; r++) acc += b2f(hp[(size_t)r * HD + col]);
    pooled[g * HD + col] = acc;
    if (blockIdx.y == 0 && threadIdx.x == 0) cnt[g] = (float)(ge - gs);
}

__global__ __launch_bounds__(256) void head_kernel(const float* __restrict__ pooled,
                                                   const float* __restrict__ cnt,
                                                   const float* __restrict__ w1,
                                                   const float* __restrict__ b1,
                                                   const float* __restrict__ w2,
                                                   const float* __restrict__ b2,
                                                   float* __restrict__ out) {
    __shared__ float prow[HD];
    __shared__ float red[256];
    int g = blockIdx.x, tid = threadIdx.x;
    float c = fmaxf(cnt[g], 1.0f);
    for (int j = tid; j < HD; j += 256) prow[j] = pooled[g * HD + j] / c;
    __syncthreads();
    float acc = b1[tid];
    for (int k = 0; k < HD; k++) acc = fmaf(prow[k], w1[k * 256 + tid], acc);
    red[tid] = fmaxf(acc, 0.0f) * w2[tid];
    __syncthreads();
    for (int s = 128; s > 0; s >>= 1) {
        if (tid < s) red[tid] += red[tid + s];
        __syncthreads();
    }
    if (tid == 0) out[g] = red[0] + b2[0];
}

// ---------------- launch ----------------------------------------------------------
extern "C" void kernel_launch(void* const* d_in, const int* in_sizes, int n_in,
                              void* d_out, int out_size, void* d_ws, size_t ws_size,
                              hipStream_t stream) {
    const float* x = (const float*)d_in[0];
    const int* eidx = (const int*)d_in[1];
    const int* batch = (const int*)d_in[2];
    const float* enc_w = (const float*)d_in[3];
    const float* enc_b = (const float*)d_in[4];
    const float* mlp_w1 = (const float*)d_in[5];
    const float* mlp_b1 = (const float*)d_in[6];
    const float* mlp_w2 = (const float*)d_in[7];
    const float* mlp_b2 = (const float*)d_in[8];
    const float* gru_wih = (const float*)d_in[9];
    const float* gru_whh = (const float*)d_in[10];
    const float* gru_bih = (const float*)d_in[11];
    const float* gru_bhh = (const float*)d_in[12];
    const float* head_w1 = (const float*)d_in[13];
    const float* head_b1 = (const float*)d_in[14];
    const float* head_w2 = (const float*)d_in[15];
    const float* head_b2 = (const float*)d_in[16];
    const int* src = eidx;
    const int* dst = eidx + N_EDGES;

    const size_t NH = (size_t)N_NODES * HD;
    char* p = (char*)d_ws;
    auto alloc = [&](size_t bytes) { char* q = p; p += (bytes + 255) & ~(size_t)255; return q; };
    bf16* S0 = (bf16*)alloc(NH * 2);
    bf16* S1 = (bf16*)alloc(NH * 2);
    bf16* S2 = (bf16*)alloc(NH * 2);
    bf16* w1tH = (bf16*)alloc((size_t)NL * HD * HD * 2);
    bf16* w1tL = (bf16*)alloc((size_t)NL * HD * HD * 2);
    bf16* w2tH = (bf16*)alloc((size_t)NL * HD * HD * 2);
    bf16* w2tL = (bf16*)alloc((size_t)NL * HD * HD * 2);
    bf16* wihtH = (bf16*)alloc((size_t)NL * 3 * HD * HD * 2);
    bf16* wihtL = (bf16*)alloc((size_t)NL * 3 * HD * HD * 2);
    bf16* whhtH = (bf16*)alloc((size_t)NL * 3 * HD * HD * 2);
    bf16* whhtL = (bf16*)alloc((size_t)NL * 3 * HD * HD * 2);
    float* pooled = (float*)alloc((size_t)N_GRAPH * HD * 4);
    float* cnt = (float*)alloc(N_GRAPH * 4);
    int* deg = (int*)alloc((N_NODES + 1) * 4);  // also cursor
    int* offs = (int*)alloc((N_NODES + 1) * 4);
    unsigned short* elist = (unsigned short*)alloc((size_t)N_EDGES * 2);
    // total ~144 MB (proven-safe envelope)

    twcvt_kernel<<<dim3(16, 16, NL), 256, 0, stream>>>(mlp_w1, w1tH, w1tL, HD);
    twcvt_kernel<<<dim3(16, 16, NL), 256, 0, stream>>>(mlp_w2, w2tH, w2tL, HD);
    twcvt_kernel<<<dim3(48, 16, NL), 256, 0, stream>>>(gru_wih, wihtH, wihtL, 3 * HD);
    twcvt_kernel<<<dim3(48, 16, NL), 256, 0, stream>>>(gru_whh, whhtH, whhtL, 3 * HD);

    hipMemsetAsync(deg, 0, (N_NODES + 1) * sizeof(int), stream);
    deg_kernel<<<(N_EDGES + 255) / 256, 256, 0, stream>>>(dst, deg);
    scan_kernel<<<1, 1024, 0, stream>>>(deg, offs);
    hipMemsetAsync(deg, 0, (N_NODES + 1) * sizeof(int), stream);
    bucket_kernel<<<(N_EDGES + 255) / 256, 256, 0, stream>>>(src, dst, offs, deg, elist);

    enc_kernel<<<N_NODES, 256, 0, stream>>>(x, enc_w, enc_b, S0);

    bf16* hcur = S0;
    bf16* hoth = S1;
    dim3 ggrid(4 * NRB);   // col-major 1-D: col = bid/NRB, row = bid%NRB
    dim3 ugrid(8 * NRB);

    for (int l = 0; l < NL; l++) {
        size_t wsq = (size_t)l * HD * HD;
        size_t wgq = (size_t)l * 3 * HD * HD;
        const float* b1 = mlp_b1 + (size_t)l * HD;
        const float* b2 = mlp_b2 + (size_t)l * HD;
        const float* bih = gru_bih + (size_t)l * 3 * HD;
        const float* bhh = gru_bhh + (size_t)l * 3 * HD;

        gemm_mfma<true><<<ggrid, 256, 0, stream>>>(hcur, w1tH + wsq, w1tL + wsq, b1, hoth, N_NODES);
        gemm_mfma<false><<<ggrid, 256, 0, stream>>>(hoth, w2tH + wsq, w2tL + wsq, b2, S2, N_NODES);
        gather_kernel<<<N_NODES, 256, 0, stream>>>(S2, hoth, elist, offs);
        gru_mfma<<<ugrid, 256, 0, stream>>>(hoth, hcur, wihtH + wgq, wihtL + wgq,
                                            whhtH + wgq, whhtL + wgq, bih, bhh, S2, N_NODES);
        bf16* newh = S2;
        S2 = hcur;
        hcur = newh;
    }

    pool_kernel<<<dim3(N_GRAPH, 2), 256, 0, stream>>>(hcur, batch, pooled, cnt);
    head_kernel<<<N_GRAPH, 256, 0, stream>>>(pooled, cnt, head_w1, head_b1, head_w2, head_b2,
                                             (float*)d_out);
}

// Round 10
// 2902.856 us; speedup vs baseline: 1.2738x; 1.0040x over previous
//
#include <hip/hip_runtime.h>
#include <hip/hip_bf16.h>
#include <math.h>

#define N_NODES 30000
#define N_EDGES 480000
#define N_GRAPH 64
#define DIN 24
#define HD 512
#define NL 6

typedef __hip_bfloat16 bf16;
using short8 = __attribute__((ext_vector_type(8))) short;
using f32x4 = __attribute__((ext_vector_type(4))) float;

// async 16B/lane global->LDS: lds dest = lp + lane*16 (wave-uniform lp!)
#define ASYNC16(gp, lp)                                              \
    __builtin_amdgcn_global_load_lds(                                \
        (const __attribute__((address_space(1))) void*)(gp),         \
        (__attribute__((address_space(3))) void*)(lp), 16, 0, 0)

__device__ __forceinline__ float sigmoidf_(float x) { return 1.0f / (1.0f + expf(-x)); }
__device__ __forceinline__ float b2f(unsigned short u) {
    return __uint_as_float(((unsigned int)u) << 16);
}
__device__ __forceinline__ unsigned short f2b(float f) {
    bf16 b = __float2bfloat16(f);
    return *(unsigned short*)&b;
}

// ---------------- encoder ---------------------------------------------------------
__global__ __launch_bounds__(256) void enc_kernel(const float* __restrict__ x,
                                                  const float* __restrict__ w,
                                                  const float* __restrict__ b,
                                                  bf16* __restrict__ h) {
    __shared__ float xs[DIN];
    int row = blockIdx.x;
    int tid = threadIdx.x;
    if (tid < DIN) xs[tid] = x[row * DIN + tid];
    __syncthreads();
    for (int c = tid; c < HD; c += 256) {
        float acc = b[c];
#pragma unroll
        for (int k = 0; k < DIN; k++) acc = fmaf(xs[k], w[k * HD + c], acc);
        h[(size_t)row * HD + c] = __float2bfloat16(acc);
    }
}

// ---------------- weight transpose + hi/lo split ----------------------------------
__global__ __launch_bounds__(256) void twcvt_kernel(const float* __restrict__ W,
                                                    bf16* __restrict__ WtH,
                                                    bf16* __restrict__ WtL, int Nc) {
    __shared__ float s[32][33];
    int l = blockIdx.z;
    const float* Wp = W + (size_t)l * HD * Nc;
    size_t ob = (size_t)l * HD * Nc;
    int k0 = blockIdx.y * 32, c0 = blockIdx.x * 32;
    int tx = threadIdx.x & 31, ty = threadIdx.x >> 5;
    for (int r = ty; r < 32; r += 8) s[r][tx] = Wp[(size_t)(k0 + r) * Nc + c0 + tx];
    __syncthreads();
    for (int r = ty; r < 32; r += 8) {
        float v = s[tx][r];
        unsigned short hu = f2b(v);
        float hf = b2f(hu);
        size_t o = ob + (size_t)(c0 + r) * HD + k0 + tx;
        *(unsigned short*)&WtH[o] = hu;
        WtL[o] = __float2bfloat16(v - hf);
    }
}

// ---------------- bf16 MFMA GEMM (hi/lo weights): tile 128x128 --------------------
// Wave owns a 32-col strip x all 128 rows (B-frags read once/wave; A reused):
// per K-step per wave: 8 A + 4 B ds_read_b128 (was 2+16).
template <bool RELU>
__global__ __launch_bounds__(256) void gemm_mfma(const bf16* __restrict__ A,
                                                 const bf16* __restrict__ WtH,
                                                 const bf16* __restrict__ WtL,
                                                 const float* __restrict__ bias,
                                                 bf16* __restrict__ C, int n) {
    __shared__ bf16 As[128 * 32];
    __shared__ bf16 BH[128 * 32];
    __shared__ bf16 BL[128 * 32];
    int tid = threadIdx.x;
    int wv = tid >> 6, lane = tid & 63;
    int quad = lane >> 4, l16 = lane & 15;
    int crow = lane >> 2, cseg = lane & 3;
    int gseg = cseg ^ ((crow >> 1) & 3);          // 2-way-free swizzle
    int fsw = (quad ^ ((l16 >> 1) & 3)) * 8;
    int row0 = blockIdx.y * 128, col0 = blockIdx.x * 128;
    f32x4 acc[2][8] = {};                         // [t][i]

    int aoff[4], alds[4];
    int boff[8];
    const bf16* wb = (wv == 2) ? WtH : WtL;
    bf16* bdst = (wv == 2) ? BH : BL;
    if (wv < 2) {
#pragma unroll
        for (int j = 0; j < 4; j++) {
            int ch = wv * 4 + j;                  // 0..7 row chunk
            int gr = row0 + ch * 16 + crow;
            if (gr > n - 1) gr = n - 1;           // clamp; dead rows guarded at write
            aoff[j] = gr * HD + gseg * 8;
            alds[j] = ch * 512;
        }
    } else {
#pragma unroll
        for (int s = 0; s < 8; s++) boff[s] = (col0 + s * 16 + crow) * HD + gseg * 8;
    }

    for (int kt = 0; kt < 512; kt += 32) {
        if (wv < 2) {
#pragma unroll
            for (int j = 0; j < 4; j++) ASYNC16(&A[aoff[j] + kt], &As[alds[j]]);
        } else {
#pragma unroll
            for (int s = 0; s < 8; s++) ASYNC16(&wb[boff[s] + kt], &bdst[s * 512]);
        }
        __syncthreads();
        short8 bhf[2], blf[2];
#pragma unroll
        for (int t = 0; t < 2; t++) {
            int fo = (wv * 32 + t * 16 + l16) * 32 + fsw;
            bhf[t] = *(const short8*)&BH[fo];
            blf[t] = *(const short8*)&BL[fo];
        }
#pragma unroll
        for (int i = 0; i < 8; i++) {
            short8 af = *(const short8*)&As[(i * 16 + l16) * 32 + fsw];
#pragma unroll
            for (int t = 0; t < 2; t++) {
                acc[t][i] = __builtin_amdgcn_mfma_f32_16x16x32_bf16(af, bhf[t], acc[t][i], 0, 0, 0);
                acc[t][i] = __builtin_amdgcn_mfma_f32_16x16x32_bf16(af, blf[t], acc[t][i], 0, 0, 0);
            }
        }
        __syncthreads();
    }
#pragma unroll
    for (int t = 0; t < 2; t++) {
        int col = col0 + wv * 32 + t * 16 + l16;
        float bb = bias[col];
#pragma unroll
        for (int i = 0; i < 8; i++) {
#pragma unroll
            for (int r = 0; r < 4; r++) {
                int row = row0 + i * 16 + quad * 4 + r;
                if (row < n) {
                    float v = acc[t][i][r] + bb;
                    if (RELU) v = fmaxf(v, 0.0f);
                    C[(size_t)row * HD + col] = __float2bfloat16(v);
                }
            }
        }
    }
}

// ---------------- fused GRU (MFMA, hi/lo, rz-concat accumulators) -----------------
// tile 128 rows x 64 cols; wave owns a 16-col strip x all 128 rows:
// per K-step per wave: 16 A + 12 B ds_read_b128 (was 4+48). LDS 64 KB, 2 blk/CU.
__global__ __launch_bounds__(256, 2) void gru_mfma(const bf16* __restrict__ M,
                                                   const bf16* __restrict__ Hc,
                                                   const bf16* __restrict__ WiH,
                                                   const bf16* __restrict__ WiL,
                                                   const bf16* __restrict__ WhH,
                                                   const bf16* __restrict__ WhL,
                                                   const float* __restrict__ bih,
                                                   const float* __restrict__ bhh,
                                                   bf16* __restrict__ Hn, int n) {
    __shared__ bf16 Ms[128 * 32];
    __shared__ bf16 Hs[128 * 32];
    __shared__ bf16 Ws[12 * 64 * 32];
    int tid = threadIdx.x;
    int wv = tid >> 6, lane = tid & 63;
    int quad = lane >> 4, l16 = lane & 15;
    int crow = lane >> 2, cseg = lane & 3;
    int gseg = cseg ^ ((crow >> 1) & 3);
    int fsw = (quad ^ ((l16 >> 1) & 3)) * 8;
    int row0 = blockIdx.y * 128, col0 = blockIdx.x * 64;
    f32x4 aR[8] = {}, aZ[8] = {}, aI[8] = {}, aHn[8] = {};

    int moff[8];
    const bf16* wgp[4];
    int wlds[4];
    if (wv == 0) {
#pragma unroll
        for (int j = 0; j < 8; j++) {
            int gr = row0 + j * 16 + crow;
            if (gr > n - 1) gr = n - 1;
            moff[j] = gr * HD + gseg * 8;
        }
    } else {
        const bf16* wbase[4] = {WiH, WiL, WhH, WhL};
#pragma unroll
        for (int pp = 0; pp < 4; pp++) {
            int p = (wv - 1) * 4 + pp;            // 0..11
            int mat = (p >= 6);
            int q = p - mat * 6;
            int g = q >> 1, pl = q & 1;
            const bf16* base = wbase[mat * 2 + pl] + (size_t)(g * HD + col0) * HD;
            wgp[pp] = base + crow * HD + gseg * 8;
            wlds[pp] = p * 2048;
        }
    }

    for (int kt = 0; kt < 512; kt += 32) {
        if (wv == 0) {
#pragma unroll
            for (int j = 0; j < 8; j++) {
                ASYNC16(&M[moff[j] + kt], &Ms[j * 512]);
                ASYNC16(&Hc[moff[j] + kt], &Hs[j * 512]);
            }
        } else {
#pragma unroll
            for (int pp = 0; pp < 4; pp++)
#pragma unroll
                for (int s = 0; s < 4; s++)
                    ASYNC16(wgp[pp] + (size_t)s * 16 * HD + kt, &Ws[wlds[pp] + s * 512]);
        }
        __syncthreads();
        // 12 B fragments for this wave's 16-col strip, held in regs
        short8 wf[12];
        int fo = (wv * 16 + l16) * 32 + fsw;
#pragma unroll
        for (int p = 0; p < 12; p++) wf[p] = *(const short8*)&Ws[p * 2048 + fo];
#pragma unroll
        for (int i = 0; i < 8; i++) {
            int ao = (i * 16 + l16) * 32 + fsw;
            short8 am = *(const short8*)&Ms[ao];
            short8 ah = *(const short8*)&Hs[ao];
            aR[i] = __builtin_amdgcn_mfma_f32_16x16x32_bf16(am, wf[0], aR[i], 0, 0, 0);
            aR[i] = __builtin_amdgcn_mfma_f32_16x16x32_bf16(am, wf[1], aR[i], 0, 0, 0);
            aR[i] = __builtin_amdgcn_mfma_f32_16x16x32_bf16(ah, wf[6], aR[i], 0, 0, 0);
            aR[i] = __builtin_amdgcn_mfma_f32_16x16x32_bf16(ah, wf[7], aR[i], 0, 0, 0);
            aZ[i] = __builtin_amdgcn_mfma_f32_16x16x32_bf16(am, wf[2], aZ[i], 0, 0, 0);
            aZ[i] = __builtin_amdgcn_mfma_f32_16x16x32_bf16(am, wf[3], aZ[i], 0, 0, 0);
            aZ[i] = __builtin_amdgcn_mfma_f32_16x16x32_bf16(ah, wf[8], aZ[i], 0, 0, 0);
            aZ[i] = __builtin_amdgcn_mfma_f32_16x16x32_bf16(ah, wf[9], aZ[i], 0, 0, 0);
            aI[i] = __builtin_amdgcn_mfma_f32_16x16x32_bf16(am, wf[4], aI[i], 0, 0, 0);
            aI[i] = __builtin_amdgcn_mfma_f32_16x16x32_bf16(am, wf[5], aI[i], 0, 0, 0);
            aHn[i] = __builtin_amdgcn_mfma_f32_16x16x32_bf16(ah, wf[10], aHn[i], 0, 0, 0);
            aHn[i] = __builtin_amdgcn_mfma_f32_16x16x32_bf16(ah, wf[11], aHn[i], 0, 0, 0);
        }
        __syncthreads();
    }
    const unsigned short* hp = (const unsigned short*)Hc;
    int col = col0 + wv * 16 + l16;
    float brz = bih[col] + bhh[col];
    float bzz = bih[HD + col] + bhh[HD + col];
    float bin_ = bih[2 * HD + col];
    float bhn_ = bhh[2 * HD + col];
#pragma unroll
    for (int i = 0; i < 8; i++) {
#pragma unroll
        for (int r = 0; r < 4; r++) {
            int row = row0 + i * 16 + quad * 4 + r;
            if (row < n) {
                float rg = sigmoidf_(aR[i][r] + brz);
                float zg = sigmoidf_(aZ[i][r] + bzz);
                float ng = tanhf(aI[i][r] + bin_ + rg * (aHn[i][r] + bhn_));
                float hold = b2f(hp[(size_t)row * HD + col]);
                Hn[(size_t)row * HD + col] = __float2bfloat16((1.0f - zg) * ng + zg * hold);
            }
        }
    }
}

// ---------------- CSR build -------------------------------------------------------
__global__ __launch_bounds__(256) void deg_kernel(const int* __restrict__ dst,
                                                  int* __restrict__ deg) {
    int e = blockIdx.x * 256 + threadIdx.x;
    if (e < N_EDGES) atomicAdd(&deg[dst[e]], 1);
}

__global__ __launch_bounds__(1024) void scan_kernel(const int* __restrict__ deg,
                                                    int* __restrict__ offs) {
    __shared__ int buf[1024];
    __shared__ int carry_s;
    int tid = threadIdx.x;
    if (tid == 0) carry_s = 0;
    __syncthreads();
    for (int base = 0; base < N_NODES; base += 1024) {
        int v = (base + tid < N_NODES) ? deg[base + tid] : 0;
        buf[tid] = v;
        __syncthreads();
        for (int s = 1; s < 1024; s <<= 1) {
            int t = (tid >= s) ? buf[tid - s] : 0;
            __syncthreads();
            buf[tid] += t;
            __syncthreads();
        }
        int incl = buf[tid];
        if (base + tid < N_NODES) offs[base + tid] = carry_s + incl - v;
        __syncthreads();
        if (tid == 0) carry_s += buf[1023];
        __syncthreads();
    }
    if (tid == 0) offs[N_NODES] = carry_s;
}

__global__ __launch_bounds__(256) void bucket_kernel(const int* __restrict__ src,
                                                     const int* __restrict__ dst,
                                                     const int* __restrict__ offs,
                                                     int* __restrict__ cursor,
                                                     unsigned short* __restrict__ elist) {
    int e = blockIdx.x * 256 + threadIdx.x;
    if (e >= N_EDGES) return;
    int d = dst[e];
    int pos = atomicAdd(&cursor[d], 1);
    elist[offs[d] + pos] = (unsigned short)src[e];
}

// ---------------- gather-sum ------------------------------------------------------
__global__ __launch_bounds__(256) void gather_kernel(const bf16* __restrict__ msg,
                                                     bf16* __restrict__ m,
                                                     const unsigned short* __restrict__ elist,
                                                     const int* __restrict__ offs) {
    int nid = blockIdx.x, tid = threadIdx.x;
    int beg = offs[nid], end = offs[nid + 1];
    const unsigned int* mp = (const unsigned int*)msg;
    unsigned int u = mp[(size_t)nid * 256 + tid];
    float ax = b2f((unsigned short)(u & 0xffffu));
    float ay = b2f((unsigned short)(u >> 16));
    int e = beg;
    for (; e + 3 < end; e += 4) {
        unsigned int v0 = mp[(size_t)elist[e] * 256 + tid];
        unsigned int v1 = mp[(size_t)elist[e + 1] * 256 + tid];
        unsigned int v2 = mp[(size_t)elist[e + 2] * 256 + tid];
        unsigned int v3 = mp[(size_t)elist[e + 3] * 256 + tid];
        ax += b2f((unsigned short)(v0 & 0xffffu)) + b2f((unsigned short)(v1 & 0xffffu)) +
              b2f((unsigned short)(v2 & 0xffffu)) + b2f((unsigned short)(v3 & 0xffffu));
        ay += b2f((unsigned short)(v0 >> 16)) + b2f((unsigned short)(v1 >> 16)) +
              b2f((unsigned short)(v2 >> 16)) + b2f((unsigned short)(v3 >> 16));
    }
    for (; e < end; e++) {
        unsigned int v0 = mp[(size_t)elist[e] * 256 + tid];
        ax += b2f((unsigned short)(v0 & 0xffffu));
        ay += b2f((unsigned short)(v0 >> 16));
    }
    unsigned int out = ((unsigned int)f2b(ay) << 16) | (unsigned int)f2b(ax);
    ((unsigned int*)m)[(size_t)nid * 256 + tid] = out;
}

// ---------------- pooling (segmented, batch sorted -> no atomics) -----------------
__global__ __launch_bounds__(256) void pool_kernel(const bf16* __restrict__ h,
                                                   const int* __restrict__ batch,
                                                   float* __restrict__ pooled,
                                                   float* __restrict__ cnt) {
    int g = blockIdx.x;
    int col = blockIdx.y * 256 + threadIdx.x;
    int lo = 0, hi = N_NODES;
    while (lo < hi) { int mid = (lo + hi) >> 1; if (batch[mid] < g) lo = mid + 1; else hi = mid; }
    int gs = lo;
    hi = N_NODES;
    while (lo < hi) { int mid = (lo + hi) >> 1; if (batch[mid] < g + 1) lo = mid + 1; else hi = mid; }
    int ge = lo;
    const unsigned short* hp = (const unsigned short*)h;
    float acc = 0.0f;
    int r = gs;
    for (; r + 3 < ge; r += 4) {
        acc += b2f(hp[(size_t)r * HD + col]) + b2f(hp[(size_t)(r + 1) * HD + col]) +
               b2f(hp[(size_t)(r + 2) * HD + col]) + b2f(hp[(size_t)(r + 3) * HD + col]);
    }
    for (; r < ge; r++) acc += b2f(hp[(size_t)r * HD + col]);
    pooled[g * HD + col] = acc;
    if (blockIdx.y == 0 && threadIdx.x == 0) cnt[g] = (float)(ge - gs);
}

__global__ __launch_bounds__(256) void head_kernel(const float* __restrict__ pooled,
                                                   const float* __restrict__ cnt,
                                                   const float* __restrict__ w1,
                                                   const float* __restrict__ b1,
                                                   const float* __restrict__ w2,
                                                   const float* __restrict__ b2,
                                                   float* __restrict__ out) {
    __shared__ float prow[HD];
    __shared__ float red[256];
    int g = blockIdx.x, tid = threadIdx.x;
    float c = fmaxf(cnt[g], 1.0f);
    for (int j = tid; j < HD; j += 256) prow[j] = pooled[g * HD + j] / c;
    __syncthreads();
    float acc = b1[tid];
    for (int k = 0; k < HD; k++) acc = fmaf(prow[k], w1[k * 256 + tid], acc);
    red[tid] = fmaxf(acc, 0.0f) * w2[tid];
    __syncthreads();
    for (int s = 128; s > 0; s >>= 1) {
        if (tid < s) red[tid] += red[tid + s];
        __syncthreads();
    }
    if (tid == 0) out[g] = red[0] + b2[0];
}

// ---------------- launch ----------------------------------------------------------
extern "C" void kernel_launch(void* const* d_in, const int* in_sizes, int n_in,
                              void* d_out, int out_size, void* d_ws, size_t ws_size,
                              hipStream_t stream) {
    const float* x = (const float*)d_in[0];
    const int* eidx = (const int*)d_in[1];
    const int* batch = (const int*)d_in[2];
    const float* enc_w = (const float*)d_in[3];
    const float* enc_b = (const float*)d_in[4];
    const float* mlp_w1 = (const float*)d_in[5];
    const float* mlp_b1 = (const float*)d_in[6];
    const float* mlp_w2 = (const float*)d_in[7];
    const float* mlp_b2 = (const float*)d_in[8];
    const float* gru_wih = (const float*)d_in[9];
    const float* gru_whh = (const float*)d_in[10];
    const float* gru_bih = (const float*)d_in[11];
    const float* gru_bhh = (const float*)d_in[12];
    const float* head_w1 = (const float*)d_in[13];
    const float* head_b1 = (const float*)d_in[14];
    const float* head_w2 = (const float*)d_in[15];
    const float* head_b2 = (const float*)d_in[16];
    const int* src = eidx;
    const int* dst = eidx + N_EDGES;

    const size_t NH = (size_t)N_NODES * HD;
    char* p = (char*)d_ws;
    auto alloc = [&](size_t bytes) { char* q = p; p += (bytes + 255) & ~(size_t)255; return q; };
    bf16* S0 = (bf16*)alloc(NH * 2);
    bf16* S1 = (bf16*)alloc(NH * 2);
    bf16* S2 = (bf16*)alloc(NH * 2);
    bf16* w1tH = (bf16*)alloc((size_t)NL * HD * HD * 2);
    bf16* w1tL = (bf16*)alloc((size_t)NL * HD * HD * 2);
    bf16* w2tH = (bf16*)alloc((size_t)NL * HD * HD * 2);
    bf16* w2tL = (bf16*)alloc((size_t)NL * HD * HD * 2);
    bf16* wihtH = (bf16*)alloc((size_t)NL * 3 * HD * HD * 2);
    bf16* wihtL = (bf16*)alloc((size_t)NL * 3 * HD * HD * 2);
    bf16* whhtH = (bf16*)alloc((size_t)NL * 3 * HD * HD * 2);
    bf16* whhtL = (bf16*)alloc((size_t)NL * 3 * HD * HD * 2);
    float* pooled = (float*)alloc((size_t)N_GRAPH * HD * 4);
    float* cnt = (float*)alloc(N_GRAPH * 4);
    int* deg = (int*)alloc((N_NODES + 1) * 4);  // also cursor
    int* offs = (int*)alloc((N_NODES + 1) * 4);
    unsigned short* elist = (unsigned short*)alloc((size_t)N_EDGES * 2);
    // total ~144 MB (proven-safe envelope)

    twcvt_kernel<<<dim3(16, 16, NL), 256, 0, stream>>>(mlp_w1, w1tH, w1tL, HD);
    twcvt_kernel<<<dim3(16, 16, NL), 256, 0, stream>>>(mlp_w2, w2tH, w2tL, HD);
    twcvt_kernel<<<dim3(48, 16, NL), 256, 0, stream>>>(gru_wih, wihtH, wihtL, 3 * HD);
    twcvt_kernel<<<dim3(48, 16, NL), 256, 0, stream>>>(gru_whh, whhtH, whhtL, 3 * HD);

    hipMemsetAsync(deg, 0, (N_NODES + 1) * sizeof(int), stream);
    deg_kernel<<<(N_EDGES + 255) / 256, 256, 0, stream>>>(dst, deg);
    scan_kernel<<<1, 1024, 0, stream>>>(deg, offs);
    hipMemsetAsync(deg, 0, (N_NODES + 1) * sizeof(int), stream);
    bucket_kernel<<<(N_EDGES + 255) / 256, 256, 0, stream>>>(src, dst, offs, deg, elist);

    enc_kernel<<<N_NODES, 256, 0, stream>>>(x, enc_w, enc_b, S0);

    bf16* hcur = S0;
    bf16* hoth = S1;
    dim3 ggrid(4, (N_NODES + 127) / 128);   // R6 2-D row-major (col = blockIdx.x -> XCD affinity)
    dim3 ugrid(8, (N_NODES + 127) / 128);

    for (int l = 0; l < NL; l++) {
        size_t wsq = (size_t)l * HD * HD;
        size_t wgq = (size_t)l * 3 * HD * HD;
        const float* b1 = mlp_b1 + (size_t)l * HD;
        const float* b2 = mlp_b2 + (size_t)l * HD;
        const float* bih = gru_bih + (size_t)l * 3 * HD;
        const float* bhh = gru_bhh + (size_t)l * 3 * HD;

        gemm_mfma<true><<<ggrid, 256, 0, stream>>>(hcur, w1tH + wsq, w1tL + wsq, b1, hoth, N_NODES);
        gemm_mfma<false><<<ggrid, 256, 0, stream>>>(hoth, w2tH + wsq, w2tL + wsq, b2, S2, N_NODES);
        gather_kernel<<<N_NODES, 256, 0, stream>>>(S2, hoth, elist, offs);
        gru_mfma<<<ugrid, 256, 0, stream>>>(hoth, hcur, wihtH + wgq, wihtL + wgq,
                                            whhtH + wgq, whhtL + wgq, bih, bhh, S2, N_NODES);
        bf16* newh = S2;
        S2 = hcur;
        hcur = newh;
    }

    pool_kernel<<<dim3(N_GRAPH, 2), 256, 0, stream>>>(hcur, batch, pooled, cnt);
    head_kernel<<<N_GRAPH, 256, 0, stream>>>(pooled, cnt, head_w1, head_b1, head_w2, head_b2,
                                             (float*)d_out);
}